// Round 11
// baseline (18696.219 us; speedup 1.0000x reference)
//
#include <hip/hip_runtime.h>
#include <hip/hip_bf16.h>

// MultilayerGRU: B=128, S=512, H=1024, L=2, O=1024
// Round 11: round-8 proven base + PX precompute group.
//  - L0 (64 WG): zr@A / g@B, self-contained chain, all-poll 64-flag barriers
//  - PX (64 WG): px[t] = h0seq[t+1] @ Wx1^T + bh1 (all 3 gates), ring-8,
//    gated only on L0F (+ lagged ring gates) -> off L1 critical chain
//  - ZG (64 WG): z (K=1024 + px addend), g (K=1024 + px addend), M-full
//  - R  (64 WG): r (K=1024 + px addend) -> rh1; OUT y[t-4] in slack
//  - h0seq/h1seq full write-once (plain cached reads safe); px/parity-rh read
//    via agent-scope atomic loads (proven round-8 mechanism)

typedef __bf16 bf16;
typedef __attribute__((ext_vector_type(8))) __bf16 bf16x8;
typedef __attribute__((ext_vector_type(4))) __bf16 bf16x4;
typedef __attribute__((ext_vector_type(4))) float f32x4;

#define MFMA16(a, b, c) __builtin_amdgcn_mfma_f32_16x16x32_bf16(a, b, c, 0, 0, 0)

static __device__ __forceinline__ bf16x8 ldfrag(const bf16* p) {
  return *reinterpret_cast<const bf16x8*>(p);
}
static __device__ __forceinline__ float sigmf(float x) { return 1.f / (1.f + __expf(-x)); }

static __device__ __forceinline__ void st2_llc(bf16* p, bf16 v) {
  unsigned u = (unsigned)__builtin_bit_cast(unsigned short, v);
  asm volatile("global_store_short %0, %1, off sc0 sc1" :: "v"(p), "v"(u) : "memory");
}
static __device__ __forceinline__ bf16x8 ldA_sc(const bf16* p) {
  union { unsigned long long q[2]; bf16x8 v; } u;
  u.q[0] = __hip_atomic_load((const unsigned long long*)p, __ATOMIC_RELAXED,
                             __HIP_MEMORY_SCOPE_AGENT);
  u.q[1] = __hip_atomic_load(((const unsigned long long*)p) + 1, __ATOMIC_RELAXED,
                             __HIP_MEMORY_SCOPE_AGENT);
  return u.v;
}
static __device__ __forceinline__ bf16x4 ld8_sc(const bf16* p) {
  unsigned long long qv = __hip_atomic_load((const unsigned long long*)p, __ATOMIC_RELAXED,
                                            __HIP_MEMORY_SCOPE_AGENT);
  return __builtin_bit_cast(bf16x4, qv);
}
static __device__ __forceinline__ void spin1(const int* p, int want) {
  while (__hip_atomic_load(p, __ATOMIC_RELAXED, __HIP_MEMORY_SCOPE_AGENT) < want)
    __builtin_amdgcn_s_sleep(1);
}
static __device__ __forceinline__ void publish(int* p, int val) {
  asm volatile("s_waitcnt vmcnt(0)" ::: "memory");
  __syncthreads();
  if (threadIdx.x == 0)
    __hip_atomic_store(p, val, __ATOMIC_RELAXED, __HIP_MEMORY_SCOPE_AGENT);
}

// ---------------- weight cast (all of Wx -> bf16) ----------------
__global__ void k_cast4(const float* __restrict__ s, bf16* __restrict__ d, int n4) {
  int i = blockIdx.x * blockDim.x + threadIdx.x;
  int st = gridDim.x * blockDim.x;
  for (; i < n4; i += st) {
    float4 v = reinterpret_cast<const float4*>(s)[i];
    bf16x4 o = {(bf16)v.x, (bf16)v.y, (bf16)v.z, (bf16)v.w};
    *reinterpret_cast<bf16x4*>(d + (size_t)i * 4) = o;
  }
}

// ---------------- gx0T[s][col][b] = (x @ Wx0^T + bh0) transposed ----------------
__global__ __launch_bounds__(256) void k_gx0T(const float* __restrict__ x,
                                              const bf16* __restrict__ wx0,
                                              const float* __restrict__ bh,
                                              bf16* __restrict__ gx0T) {
  const int lane = threadIdx.x & 63;
  const int gw = blockIdx.x * 4 + (threadIdx.x >> 6);
  const int NT = 3072 / 64;
  const int tm = gw / NT, tn = gw % NT;
  const int m0 = tm * 64, n0 = tn * 64;
  const int r = lane & 15, kq = lane >> 4;
  f32x4 acc[4][4] = {};
  for (int k0 = 0; k0 < 1024; k0 += 32) {
    const int k = k0 + kq * 8;
    bf16x8 a[4], b[4];
#pragma unroll
    for (int mi = 0; mi < 4; ++mi) {
      const int m = m0 + mi * 16 + r;
      const int bb = m & 127, s = m >> 7;
      const float* xp = x + ((size_t)(bb * 512 + s)) * 1024 + k;
      float4 lo = *reinterpret_cast<const float4*>(xp);
      float4 hi = *reinterpret_cast<const float4*>(xp + 4);
      bf16x8 av;
      av[0] = (bf16)lo.x; av[1] = (bf16)lo.y; av[2] = (bf16)lo.z; av[3] = (bf16)lo.w;
      av[4] = (bf16)hi.x; av[5] = (bf16)hi.y; av[6] = (bf16)hi.z; av[7] = (bf16)hi.w;
      a[mi] = av;
    }
#pragma unroll
    for (int ni = 0; ni < 4; ++ni)
      b[ni] = ldfrag(wx0 + (size_t)(n0 + ni * 16 + r) * 1024 + k);
#pragma unroll
    for (int mi = 0; mi < 4; ++mi)
#pragma unroll
      for (int ni = 0; ni < 4; ++ni) acc[mi][ni] = MFMA16(a[mi], b[ni], acc[mi][ni]);
  }
#pragma unroll
  for (int mi = 0; mi < 4; ++mi) {
#pragma unroll
    for (int ni = 0; ni < 4; ++ni) {
      const int col = n0 + ni * 16 + r;
      const float bias = bh[col];
      bf16x4 v;
#pragma unroll
      for (int j = 0; j < 4; ++j) v[j] = (bf16)(acc[mi][ni][j] + bias);
      const int m = m0 + mi * 16 + kq * 4;
      const int s = m >> 7, bb = m & 127;
      *reinterpret_cast<bf16x4*>(gx0T + ((size_t)s * 3072 + col) * 128 + bb) = v;
    }
  }
}

// ---------------- persistent GRU scan ----------------
struct GP {
  const float* Wh;
  const float* bh;
  const float* by;
  const float* Why;
  const bf16* Wxb;   // all Wx cast to bf16 [2][3][1024][1024]
  const bf16* gx0T;
  bf16* h0seq;       // 513 x [128][1024] write-once
  bf16* h1seq;       // 513 x write-once
  bf16* rh0seq;      // 512 x (or 2 parity)
  bf16* rh1seq;
  bf16* pxring;      // 8 x [3072][128]
  float* out;
  int* bar;
  int sc_rh;
};

__device__ __forceinline__ void stage_row8(char* dst, int row, int rb, int k8,
                                           const float* __restrict__ src) {
  const float4 f0 = *reinterpret_cast<const float4*>(src);
  const float4 f1 = *reinterpret_cast<const float4*>(src + 4);
  bf16x8 v;
  v[0] = (bf16)f0.x; v[1] = (bf16)f0.y; v[2] = (bf16)f0.z; v[3] = (bf16)f0.w;
  v[4] = (bf16)f1.x; v[5] = (bf16)f1.y; v[6] = (bf16)f1.z; v[7] = (bf16)f1.w;
  *reinterpret_cast<bf16x8*>(dst + (size_t)row * rb + ((k8 * 2) ^ ((row & 7) << 4))) = v;
}

// A = activations (global), B = weights (LDS, XOR-swizzled), K=1024
template <int MT, int NT, bool SC>
__device__ __forceinline__ void mmA(const bf16* __restrict__ A, const char* __restrict__ ldsb,
                                    f32x4 (&acc)[MT][NT], const int m0, const int r,
                                    const int kq) {
#pragma unroll 8
  for (int k0 = 0; k0 < 1024; k0 += 32) {
    const int k = k0 + kq * 8;
    bf16x8 a[MT];
#pragma unroll
    for (int mi = 0; mi < MT; ++mi) {
      const bf16* p = A + (size_t)(m0 + mi * 16 + r) * 1024 + k;
      a[mi] = SC ? ldA_sc(p) : ldfrag(p);
    }
#pragma unroll
    for (int nt = 0; nt < NT; ++nt) {
      const bf16x8 b = *reinterpret_cast<const bf16x8*>(
          ldsb + (size_t)(nt * 16 + r) * 2048 + ((k * 2) ^ ((r & 7) << 4)));
#pragma unroll
      for (int mi = 0; mi < MT; ++mi) acc[mi][nt] = MFMA16(a[mi], b, acc[mi][nt]);
    }
  }
}

__global__ void __launch_bounds__(256, 1) k_gru(GP P) {
  extern __shared__ char lds[];
  const int w = blockIdx.x;
  const int tid = threadIdx.x;
  const int r16 = tid & 15, q = (tid >> 4) & 3, wv = tid >> 6;
  const size_t HB = 131072;
  const size_t PXS = 393216;  // px slot elems
  int* L0F = P.bar;        // 64
  int* ZGF = P.bar + 64;   // 64
  int* RF = P.bar + 128;   // 64
  int* PXF = P.bar + 192;  // 64
  const int m0w = wv * 32;
  float* hid = P.out + (size_t)128 * 512 * 1024;

  if (w < 64) {
    // =================== L0 chain (self-contained) ===================
    const int c0 = w * 16;
    for (int ch = tid; ch < 32 * 128; ch += 256) {  // rows 0-15 z, 16-31 r
      const int row = ch >> 7, k8 = (ch & 127) * 8;
      const int gate = row >> 4, col = c0 + (row & 15);
      stage_row8(lds, row, 2048, k8, P.Wh + ((size_t)(gate * 1024 + col)) * 1024 + k8);
    }
    for (int ch = tid; ch < 16 * 128; ch += 256) {  // g
      const int row = ch >> 7, k8 = (ch & 127) * 8;
      stage_row8(lds + 65536, row, 2048, k8,
                 P.Wh + ((size_t)(2 * 1024 + c0 + row)) * 1024 + k8);
    }
    __syncthreads();
    float h0reg[2][4] = {}, z0[2][4];
    bf16x4 pz[2], pr[2], pg[2];
#pragma unroll
    for (int f = 0; f < 2; ++f) {
      const bf16* gxz = P.gx0T + (size_t)(c0 + r16) * 128 + m0w + f * 16 + q * 4;
      pz[f] = *reinterpret_cast<const bf16x4*>(gxz);
      pr[f] = *reinterpret_cast<const bf16x4*>(gxz + (size_t)1024 * 128);
    }
    for (int t = 0; t < 512; ++t) {
      if (t) {
        if (tid < 64) spin1(L0F + tid, 2 * t);
        __syncthreads();
      }
#pragma unroll
      for (int f = 0; f < 2; ++f)
        pg[f] = *reinterpret_cast<const bf16x4*>(
            P.gx0T + ((size_t)t * 3072 + 2048 + c0 + r16) * 128 + m0w + f * 16 + q * 4);
      f32x4 acc[2][2] = {};
      mmA<2, 2, false>(P.h0seq + (size_t)t * HB, lds, acc, m0w, r16, q);
      bf16* rh0t = P.rh0seq + (size_t)(P.sc_rh ? (t & 1) : t) * HB;
#pragma unroll
      for (int f = 0; f < 2; ++f)
#pragma unroll
        for (int j = 0; j < 4; ++j) {
          const int m = m0w + f * 16 + q * 4 + j;
          z0[f][j] = sigmf(acc[f][0][j] + (float)pz[f][j]);
          const float rv = sigmf(acc[f][1][j] + (float)pr[f][j]);
          st2_llc(rh0t + (size_t)m * 1024 + c0 + r16, (bf16)(rv * h0reg[f][j]));
        }
      publish(L0F + w, 2 * t + 1);

      if (tid < 64) spin1(L0F + tid, 2 * t + 1);
      __syncthreads();
      if (t + 1 < 512) {
#pragma unroll
        for (int f = 0; f < 2; ++f) {
          const bf16* gxz =
              P.gx0T + ((size_t)(t + 1) * 3072 + c0 + r16) * 128 + m0w + f * 16 + q * 4;
          pz[f] = *reinterpret_cast<const bf16x4*>(gxz);
          pr[f] = *reinterpret_cast<const bf16x4*>(gxz + (size_t)1024 * 128);
        }
      }
      f32x4 ac2[2][1] = {};
      if (P.sc_rh) mmA<2, 1, true>(rh0t, lds + 65536, ac2, m0w, r16, q);
      else mmA<2, 1, false>(rh0t, lds + 65536, ac2, m0w, r16, q);
      bf16* hsn = P.h0seq + (size_t)(t + 1) * HB;
#pragma unroll
      for (int f = 0; f < 2; ++f)
#pragma unroll
        for (int j = 0; j < 4; ++j) {
          const int m = m0w + f * 16 + q * 4 + j;
          const float gv = tanhf(ac2[f][0][j] + (float)pg[f][j]);
          const float hn = z0[f][j] * h0reg[f][j] + (1.f - z0[f][j]) * gv;
          h0reg[f][j] = hn;
          st2_llc(hsn + (size_t)m * 1024 + c0 + r16, (bf16)hn);
        }
      publish(L0F + w, 2 * t + 2);
    }
#pragma unroll
    for (int f = 0; f < 2; ++f)
#pragma unroll
      for (int j = 0; j < 4; ++j)
        hid[(size_t)(m0w + f * 16 + q * 4 + j) * 2048 + c0 + r16] = h0reg[f][j];

  } else if (w < 128) {
    // =================== ZG: z + g, M-full, K=1024 each ===================
    const int idx = w - 64, c0 = idx * 16;
    for (int ch = tid; ch < 16 * 128; ch += 256) {  // Wh1z
      const int row = ch >> 7, k8 = (ch & 127) * 8;
      stage_row8(lds, row, 2048, k8, P.Wh + ((size_t)(3 * 1024 + c0 + row)) * 1024 + k8);
    }
    for (int ch = tid; ch < 16 * 128; ch += 256) {  // Wh1g
      const int row = ch >> 7, k8 = (ch & 127) * 8;
      stage_row8(lds + 32768, row, 2048, k8,
                 P.Wh + ((size_t)(5 * 1024 + c0 + row)) * 1024 + k8);
    }
    __syncthreads();
    float h1reg[2][4] = {}, z1[2][4];
    for (int t = 0; t < 512; ++t) {
      if (tid < 64) spin1(ZGF + tid, t);
      else if (tid < 128) spin1(PXF + tid - 64, t + 1);
      __syncthreads();
      const bf16* pxt = P.pxring + (size_t)(t & 7) * PXS;
      bf16x4 pxz[2], pxg[2];
#pragma unroll
      for (int f = 0; f < 2; ++f) {
        const size_t mo = m0w + f * 16 + q * 4;
        pxz[f] = ld8_sc(pxt + (size_t)(c0 + r16) * 128 + mo);
        pxg[f] = ld8_sc(pxt + (size_t)(2048 + c0 + r16) * 128 + mo);
      }
      f32x4 acc[2][1] = {};
      mmA<2, 1, false>(P.h1seq + (size_t)t * HB, lds, acc, m0w, r16, q);
#pragma unroll
      for (int f = 0; f < 2; ++f)
#pragma unroll
        for (int j = 0; j < 4; ++j) z1[f][j] = sigmf(acc[f][0][j] + (float)pxz[f][j]);

      if (tid < 64) spin1(RF + tid, t + 1);
      __syncthreads();
      const bf16* rh1t = P.rh1seq + (size_t)(P.sc_rh ? (t & 1) : t) * HB;
      f32x4 ac2[2][1] = {};
      if (P.sc_rh) mmA<2, 1, true>(rh1t, lds + 32768, ac2, m0w, r16, q);
      else mmA<2, 1, false>(rh1t, lds + 32768, ac2, m0w, r16, q);
      bf16* hsn = P.h1seq + (size_t)(t + 1) * HB;
#pragma unroll
      for (int f = 0; f < 2; ++f)
#pragma unroll
        for (int j = 0; j < 4; ++j) {
          const int m = m0w + f * 16 + q * 4 + j;
          const float gv = tanhf(ac2[f][0][j] + (float)pxg[f][j]);
          const float hn = z1[f][j] * h1reg[f][j] + (1.f - z1[f][j]) * gv;
          h1reg[f][j] = hn;
          st2_llc(hsn + (size_t)m * 1024 + c0 + r16, (bf16)hn);
        }
      publish(ZGF + idx, t + 1);
    }
#pragma unroll
    for (int f = 0; f < 2; ++f)
#pragma unroll
      for (int j = 0; j < 4; ++j)
        hid[(size_t)(m0w + f * 16 + q * 4 + j) * 2048 + 1024 + c0 + r16] = h1reg[f][j];

  } else if (w < 192) {
    // =================== R: r -> rh1 ; OUT in slack ===================
    const int idx = w - 128, c0 = idx * 16;
    for (int ch = tid; ch < 16 * 128; ch += 256) {  // Wh1r
      const int row = ch >> 7, k8 = (ch & 127) * 8;
      stage_row8(lds, row, 2048, k8, P.Wh + ((size_t)(4 * 1024 + c0 + row)) * 1024 + k8);
    }
    for (int ch = tid; ch < 16 * 128; ch += 256) {  // Why
      const int row = ch >> 7, k8 = (ch & 127) * 8;
      stage_row8(lds + 32768, row, 2048, k8, P.Why + ((size_t)(c0 + row)) * 1024 + k8);
    }
    __syncthreads();
    const float byv = P.by[c0 + r16];
    for (int t = 0; t < 512; ++t) {
      if (tid < 64) spin1(ZGF + tid, t);
      else if (tid < 128) spin1(PXF + tid - 64, t + 1);
      __syncthreads();
      const bf16* pxt = P.pxring + (size_t)(t & 7) * PXS;
      bf16x4 pxr[2];
#pragma unroll
      for (int f = 0; f < 2; ++f)
        pxr[f] = ld8_sc(pxt + (size_t)(1024 + c0 + r16) * 128 + m0w + f * 16 + q * 4);
      const bf16* h1p = P.h1seq + (size_t)t * HB;
      f32x4 acc[2][1] = {};
      mmA<2, 1, false>(h1p, lds, acc, m0w, r16, q);
      bf16* rh1t = P.rh1seq + (size_t)(P.sc_rh ? (t & 1) : t) * HB;
#pragma unroll
      for (int f = 0; f < 2; ++f)
#pragma unroll
        for (int j = 0; j < 4; ++j) {
          const int m = m0w + f * 16 + q * 4 + j;
          const float rv = sigmf(acc[f][0][j] + (float)pxr[f][j]);
          const float hpv = (float)h1p[(size_t)m * 1024 + c0 + r16];
          st2_llc(rh1t + (size_t)m * 1024 + c0 + r16, (bf16)(rv * hpv));
        }
      publish(RF + idx, t + 1);

      if (t >= 4) {  // OUT: y[t-4] = h1seq[t-3] @ Why^T + by (zero wait)
        const int o = t - 4;
        f32x4 a3[2][1] = {};
        mmA<2, 1, false>(P.h1seq + (size_t)(o + 1) * HB, lds + 32768, a3, m0w, r16, q);
#pragma unroll
        for (int f = 0; f < 2; ++f)
#pragma unroll
          for (int j = 0; j < 4; ++j) {
            const int m = m0w + f * 16 + q * 4 + j;
            P.out[((size_t)m * 512 + o) * 1024 + c0 + r16] = a3[f][0][j] + byv;
          }
      }
    }
    for (int o = 508; o < 512; ++o) {  // tail OUTs
      if (tid < 64) spin1(ZGF + tid, o + 1);
      __syncthreads();
      f32x4 a3[2][1] = {};
      mmA<2, 1, false>(P.h1seq + (size_t)(o + 1) * HB, lds + 32768, a3, m0w, r16, q);
#pragma unroll
      for (int f = 0; f < 2; ++f)
#pragma unroll
        for (int j = 0; j < 4; ++j) {
          const int m = m0w + f * 16 + q * 4 + j;
          P.out[((size_t)m * 512 + o) * 1024 + c0 + r16] = a3[f][0][j] + byv;
        }
    }

  } else {
    // =================== PX: px[j] = h0seq[j+1] @ Wx1^T + bh1, ring-8 ===========
    const int idx = w - 192, c0 = idx * 48;
    const bf16* Wp[3];
    float bias[3];
#pragma unroll
    for (int nt = 0; nt < 3; ++nt) {
      const int cb = c0 + nt * 16;
      const int gate = cb >> 10, row0 = (cb & 1023) + r16;
      Wp[nt] = P.Wxb + ((size_t)((3 + gate) * 1024 + row0)) * 1024;
      bias[nt] = P.bh[3072 + cb + r16];
    }
    for (int j = 0; j < 512; ++j) {
      if (tid < 64) spin1(L0F + tid, 2 * (j + 1));
      else if (tid < 128) { if (j >= 8) spin1(ZGF + tid - 64, j - 7); }
      else if (tid < 192) { if (j >= 8) spin1(RF + tid - 128, j - 7); }
      __syncthreads();
      const bf16* h0 = P.h0seq + (size_t)(j + 1) * HB;
      f32x4 acc[2][3] = {};
#pragma unroll 8
      for (int k0 = 0; k0 < 1024; k0 += 32) {
        const int k = k0 + q * 8;
        const bf16x8 a0 = ldfrag(h0 + (size_t)(m0w + r16) * 1024 + k);
        const bf16x8 a1 = ldfrag(h0 + (size_t)(m0w + 16 + r16) * 1024 + k);
#pragma unroll
        for (int nt = 0; nt < 3; ++nt) {
          const bf16x8 b = ldfrag(Wp[nt] + k);
          acc[0][nt] = MFMA16(a0, b, acc[0][nt]);
          acc[1][nt] = MFMA16(a1, b, acc[1][nt]);
        }
      }
      bf16* pxt = P.pxring + (size_t)(j & 7) * PXS;
#pragma unroll
      for (int nt = 0; nt < 3; ++nt) {
        const int col = c0 + nt * 16 + r16;
#pragma unroll
        for (int f = 0; f < 2; ++f)
#pragma unroll
          for (int jj = 0; jj < 4; ++jj) {
            const int m = m0w + f * 16 + q * 4 + jj;
            st2_llc(pxt + (size_t)col * 128 + m, (bf16)(acc[f][nt][jj] + bias[nt]));
          }
      }
      publish(PXF + idx, j + 1);
    }
  }
}

extern "C" void kernel_launch(void* const* d_in, const int* in_sizes, int n_in,
                              void* d_out, int out_size, void* d_ws, size_t ws_size,
                              hipStream_t stream) {
  const float* x = (const float*)d_in[0];
  const float* Wx = (const float*)d_in[1];
  const float* Wh = (const float*)d_in[2];
  const float* bh = (const float*)d_in[3];
  const float* Why = (const float*)d_in[4];
  const float* by = (const float*)d_in[5];
  float* out = (float*)d_out;

  const size_t HBb = (size_t)131072 * 2;
  auto al = [](size_t v) { return (v + 255) & ~(size_t)255; };
  const size_t szWxb = al((size_t)6291456 * 2);              // 12.6 MB
  const size_t szGx = al((size_t)512 * 3072 * 128 * 2);      // 384 MB
  const size_t szHseq = al((size_t)513 * HBb);               // 134.5 MB
  const size_t szRhFull = al((size_t)512 * HBb);
  const size_t szRhPar = al((size_t)2 * HBb);
  const size_t szPx = al((size_t)8 * 3072 * 128 * 2);        // 6.3 MB
  const size_t szBar = 4096;
  const size_t needFull = szWxb + szGx + 2 * szHseq + 2 * szRhFull + szPx + szBar;
  const int sc_rh = (ws_size >= needFull) ? 0 : 1;
  const size_t szRh = sc_rh ? szRhPar : szRhFull;

  char* ws = (char*)d_ws;
  size_t off = 0;
  auto alloc = [&](size_t bytes) -> void* {
    void* p = ws + off;
    off += bytes;
    return p;
  };
  bf16* Wxb = (bf16*)alloc(szWxb);
  bf16* gx0T = (bf16*)alloc(szGx);
  bf16* h0seq = (bf16*)alloc(szHseq);
  bf16* h1seq = (bf16*)alloc(szHseq);
  bf16* rh0seq = (bf16*)alloc(szRh);
  bf16* rh1seq = (bf16*)alloc(szRh);
  bf16* pxring = (bf16*)alloc(szPx);
  int* bar = (int*)alloc(szBar);

  hipFuncSetAttribute((const void*)k_gru, hipFuncAttributeMaxDynamicSharedMemorySize, 98304);

  k_cast4<<<1024, 256, 0, stream>>>(Wx, Wxb, 6291456 / 4);
  hipMemsetAsync(h0seq, 0, 262144, stream);  // h0seq[0] = 0
  hipMemsetAsync(h1seq, 0, 262144, stream);  // h1seq[0] = 0
  hipMemsetAsync(bar, 0, szBar, stream);

  k_gx0T<<<12288, 256, 0, stream>>>(x, Wxb, bh, gx0T);

  GP gp{Wh, bh, by, Why, Wxb, gx0T, h0seq, h1seq, rh0seq, rh1seq, pxring, out, bar, sc_rh};
  void* kargs[] = {&gp};
  hipLaunchCooperativeKernel((void*)k_gru, dim3(256), dim3(256), kargs, 98304, stream);
}